// Round 2
// baseline (5035.131 us; speedup 1.0000x reference)
//
#include <hip/hip_runtime.h>

#define NB   8
#define NP   8192
#define NS   2048
#define NK   16
#define DIN  64
#define DOUT 128
#define BN_EPS 1e-5f

// ---------------- K0: fold BN into weights, transpose to [k][o] ----------------
__global__ void fold_weights_kernel(const float* __restrict__ W, const float* __restrict__ bias,
                                    const float* __restrict__ gamma, const float* __restrict__ beta,
                                    const float* __restrict__ rmean, const float* __restrict__ rvar,
                                    float* __restrict__ Wt, float* __restrict__ Cb)
{
    int i = blockIdx.x * 256 + threadIdx.x;
    if (i < DIN * DOUT) {
        int o = i & (DOUT - 1);
        int k = i >> 7;
        float sc = gamma[o] * rsqrtf(rvar[o] + BN_EPS);
        Wt[i] = W[o * DIN + k] * sc;            // Wt[k*128 + o]
        if (i < DOUT) {
            Cb[i] = (bias[i] - rmean[i]) * sc + beta[i];
        }
    }
}

// ---------------- K1: farthest point sampling (1 block per batch) ----------------
// 1024 threads x 8 pts/thread: arrays fit in VGPRs (no scratch spill),
// 4 waves/SIMD hide shuffle+LDS latency. launch_bounds(1024) caps VGPR at 128.
#define FT 1024
#define FP (NP / FT)   // 8 points per thread
#define FW (FT / 64)   // 16 waves

__global__ __launch_bounds__(FT)
void fps_kernel(const float* __restrict__ coords, float* __restrict__ out_coords)
{
#pragma clang fp contract(off)
    __shared__ float sx[NP], sy[NP], sz[NP];   // 96 KB
    __shared__ float rv[2][FW];
    __shared__ int   ri[2][FW];

    const int b = blockIdx.x, t = threadIdx.x;
    const float* cb = coords + (size_t)b * NP * 3;

    for (int i = t; i < NP; i += FT) {
        sx[i] = cb[i * 3 + 0];
        sy[i] = cb[i * 3 + 1];
        sz[i] = cb[i * 3 + 2];
    }
    __syncthreads();

    float px[FP], py[FP], pz[FP], dist[FP];
#pragma unroll
    for (int k = 0; k < FP; ++k) {
        int i = t + k * FT;
        px[k] = sx[i]; py[k] = sy[i]; pz[k] = sz[i];
        dist[k] = 1e10f;
    }

    const int wave = t >> 6, lane = t & 63;
    int cur = 0;
    float* ocb = out_coords + (size_t)b * NS * 3;

    for (int s = 0; s < NS; ++s) {
        float cx = sx[cur], cy = sy[cur], cz = sz[cur];
        if (t == 0) {
            ocb[s * 3 + 0] = cx; ocb[s * 3 + 1] = cy; ocb[s * 3 + 2] = cz;
        }
        // update min-dist + local argmax (strict > keeps smallest k = smallest global idx)
        float m = -1.0f; int kk = 0;
#pragma unroll
        for (int k = 0; k < FP; ++k) {
            float dx = px[k] - cx, dy = py[k] - cy, dz = pz[k] - cz;
            float d = ((dx * dx) + (dy * dy)) + (dz * dz);
            float nd = dist[k] < d ? dist[k] : d;
            dist[k] = nd;
            if (nd > m) { m = nd; kk = k; }
        }
        int li = t + kk * FT;
        // wave reduce: max value, tie -> min index
#pragma unroll
        for (int off = 32; off >= 1; off >>= 1) {
            float om = __shfl_xor(m, off);
            int   oi = __shfl_xor(li, off);
            if (om > m || (om == m && oi < li)) { m = om; li = oi; }
        }
        int pb = s & 1;
        if (lane == 0) { rv[pb][wave] = m; ri[pb][wave] = li; }
        __syncthreads();
        // every thread redundantly scans 16 wave-partials (LDS broadcast reads)
        float bm = rv[pb][0]; int bi = ri[pb][0];
#pragma unroll
        for (int w = 1; w < FW; ++w) {
            float vm = rv[pb][w]; int vi = ri[pb][w];
            if (vm > bm || (vm == bm && vi < bi)) { bm = vm; bi = vi; }
        }
        cur = bi;
    }
}

// ---------------- K2: pointwise MLP (conv1x1 + folded BN + relu) ----------------
__global__ __launch_bounds__(256)
void mlp_kernel(const float* __restrict__ feat, const float* __restrict__ Wt,
                const float* __restrict__ Cb, float* __restrict__ h)
{
    __shared__ float sf[2][DIN];
    const int t = threadIdx.x;
    const int o = t & (DOUT - 1);
    const int r2 = t >> 7;
    const size_t row0 = (size_t)blockIdx.x * 2;

    if (t < 2 * DIN) sf[t >> 6][t & 63] = feat[row0 * DIN + t];
    __syncthreads();

    float acc = Cb[o];
    const float4* f4 = (const float4*)sf[r2];
#pragma unroll
    for (int k4 = 0; k4 < DIN / 4; ++k4) {
        float4 f = f4[k4];
        acc = fmaf(f.x, Wt[(k4 * 4 + 0) * DOUT + o], acc);
        acc = fmaf(f.y, Wt[(k4 * 4 + 1) * DOUT + o], acc);
        acc = fmaf(f.z, Wt[(k4 * 4 + 2) * DOUT + o], acc);
        acc = fmaf(f.w, Wt[(k4 * 4 + 3) * DOUT + o], acc);
    }
    h[(row0 + r2) * DOUT + o] = fmaxf(acc, 0.0f);
}

// ---------------- K3: exact KNN (block per query, radix-cut + parallel rank-select) ----------------
#define KT 256
#define KJ (NP / KT)   // 32
#define NBINS 256
#define MAXC 512

__global__ __launch_bounds__(KT)
void knn_kernel(const float* __restrict__ coords, const float* __restrict__ qc,
                int* __restrict__ knn)
{
#pragma clang fp contract(off)
    __shared__ float sdist[NP];
    __shared__ unsigned hist[NBINS];
    __shared__ float cd[MAXC];
    __shared__ int   ci[MAXC];
    __shared__ unsigned ccnt;
    __shared__ int s_cut;

    const int q = blockIdx.x;
    const int b = q >> 11;
    const int t = threadIdx.x;
    const float* cb = coords + (size_t)b * NP * 3;
    const float qx = qc[(size_t)q * 3 + 0];
    const float qy = qc[(size_t)q * 3 + 1];
    const float qz = qc[(size_t)q * 3 + 2];

    for (int i = t; i < NBINS; i += KT) hist[i] = 0;
    if (t == 0) ccnt = 0;
    __syncthreads();

    for (int j = 0; j < KJ; ++j) {
        int i = t + j * KT;
        float dx = cb[i * 3 + 0] - qx, dy = cb[i * 3 + 1] - qy, dz = cb[i * 3 + 2] - qz;
        float d = ((dx * dx) + (dy * dy)) + (dz * dz);
        sdist[i] = d;
        atomicAdd(&hist[__float_as_uint(d) >> 23], 1u);   // positive floats: exponent bins
    }
    __syncthreads();

    // one wave finds the cut bin (cum count crosses NK)
    if (t < 64) {
        unsigned c0 = hist[t * 4 + 0], c1 = hist[t * 4 + 1];
        unsigned c2 = hist[t * 4 + 2], c3 = hist[t * 4 + 3];
        unsigned lsum = c0 + c1 + c2 + c3;
        unsigned incl = lsum;
#pragma unroll
        for (int off = 1; off < 64; off <<= 1) {
            unsigned n = __shfl_up(incl, off);
            if (t >= off) incl += n;
        }
        unsigned run = incl - lsum;
        if (run < NK && run + c0 >= NK) s_cut = t * 4 + 0;
        run += c0;
        if (run < NK && run + c1 >= NK) s_cut = t * 4 + 1;
        run += c1;
        if (run < NK && run + c2 >= NK) s_cut = t * 4 + 2;
        run += c2;
        if (run < NK && run + c3 >= NK) s_cut = t * 4 + 3;
    }
    __syncthreads();

    const int cut = s_cut;
    for (int j = 0; j < KJ; ++j) {
        int i = t + j * KT;
        float d = sdist[i];
        if ((int)(__float_as_uint(d) >> 23) <= cut) {
            unsigned p = atomicAdd(&ccnt, 1u);
            if (p < MAXC) { cd[p] = d; ci[p] = i; }
        }
    }
    __syncthreads();

    // parallel rank-select: candidate's rank = #{(dj,ij) < (d,i)} lexicographic.
    // Ranks are unique; rank < NK writes its slot directly. One pass, no serial tail.
    int cnt = (int)(ccnt < (unsigned)MAXC ? ccnt : (unsigned)MAXC);
    for (int p = t; p < cnt; p += KT) {
        float d = cd[p]; int idx = ci[p];
        int rank = 0;
        for (int j = 0; j < cnt; ++j) {
            float dj = cd[j]; int ij = ci[j];
            rank += (dj < d || (dj == d && ij < idx)) ? 1 : 0;
        }
        if (rank < NK) knn[(size_t)q * NK + rank] = idx;
    }
}

// ---------------- K4: gather precomputed h + max-pool ----------------
__global__ __launch_bounds__(128)
void gather_max_kernel(const float* __restrict__ h, const int* __restrict__ knn,
                       float* __restrict__ outF)
{
    const int q = blockIdx.x, o = threadIdx.x, b = q >> 11;
    __shared__ int sidx[NK];
    if (o < NK) sidx[o] = knn[(size_t)q * NK + o];
    __syncthreads();
    float m = -3.4e38f;
#pragma unroll
    for (int n = 0; n < NK; ++n) {
        float v = h[((size_t)b * NP + sidx[n]) * DOUT + o];
        m = fmaxf(m, v);
    }
    outF[(size_t)q * DOUT + o] = m;
}

// ---------------- K4': fallback if ws too small — fused gather + MLP + max ----------------
__global__ __launch_bounds__(128)
void fused_gather_mlp_kernel(const float* __restrict__ feat, const float* __restrict__ Wt,
                             const float* __restrict__ Cb, const int* __restrict__ knn,
                             float* __restrict__ outF)
{
    const int q = blockIdx.x, o = threadIdx.x, b = q >> 11;
    __shared__ int sidx[NK];
    __shared__ float sf[NK][DIN];
    if (o < NK) sidx[o] = knn[(size_t)q * NK + o];
    __syncthreads();
    for (int j = o; j < NK * DIN; j += 128) {
        int n = j >> 6;
        sf[n][j & 63] = feat[((size_t)b * NP + sidx[n]) * DIN + (j & 63)];
    }
    __syncthreads();
    const float cb0 = Cb[o];
    float m = -3.4e38f;
    for (int n = 0; n < NK; ++n) {
        float acc = cb0;
        const float4* f4 = (const float4*)sf[n];
#pragma unroll
        for (int k4 = 0; k4 < DIN / 4; ++k4) {
            float4 f = f4[k4];
            acc = fmaf(f.x, Wt[(k4 * 4 + 0) * DOUT + o], acc);
            acc = fmaf(f.y, Wt[(k4 * 4 + 1) * DOUT + o], acc);
            acc = fmaf(f.z, Wt[(k4 * 4 + 2) * DOUT + o], acc);
            acc = fmaf(f.w, Wt[(k4 * 4 + 3) * DOUT + o], acc);
        }
        m = fmaxf(m, fmaxf(acc, 0.0f));
    }
    outF[(size_t)q * DOUT + o] = m;
}

extern "C" void kernel_launch(void* const* d_in, const int* in_sizes, int n_in,
                              void* d_out, int out_size, void* d_ws, size_t ws_size,
                              hipStream_t stream)
{
    const float* coords = (const float*)d_in[0];
    const float* feat   = (const float*)d_in[1];
    const float* W      = (const float*)d_in[2];
    const float* bias   = (const float*)d_in[3];
    const float* gamma  = (const float*)d_in[4];
    const float* beta   = (const float*)d_in[5];
    const float* rmean  = (const float*)d_in[6];
    const float* rvar   = (const float*)d_in[7];

    float* out_coords = (float*)d_out;                    // [8,2048,3]
    float* out_feat   = out_coords + (size_t)NB * NS * 3; // [8,2048,128]

    char* ws = (char*)d_ws;
    float* Wt = (float*)ws;                                   // 32 KB
    float* Cb = (float*)(ws + 32768);                         // 512 B
    int*   knn = (int*)(ws + 65536);                          // 1 MB
    size_t knn_bytes = (size_t)NB * NS * NK * 4;
    float* h = (float*)(ws + 65536 + knn_bytes);              // 33.5 MB
    size_t need_h = (size_t)NB * NP * DOUT * 4;
    bool pathA = ws_size >= 65536 + knn_bytes + need_h;

    fold_weights_kernel<<<(DIN * DOUT + 255) / 256, 256, 0, stream>>>(
        W, bias, gamma, beta, rmean, rvar, Wt, Cb);
    if (pathA)
        mlp_kernel<<<NB * NP / 2, 256, 0, stream>>>(feat, Wt, Cb, h);
    fps_kernel<<<NB, FT, 0, stream>>>(coords, out_coords);
    knn_kernel<<<NB * NS, KT, 0, stream>>>(coords, out_coords, knn);
    if (pathA)
        gather_max_kernel<<<NB * NS, 128, 0, stream>>>(h, knn, out_feat);
    else
        fused_gather_mlp_kernel<<<NB * NS, 128, 0, stream>>>(feat, Wt, Cb, knn, out_feat);
}

// Round 3
// 3812.491 us; speedup vs baseline: 1.3207x; 1.3207x over previous
//
#include <hip/hip_runtime.h>

#define NB   8
#define NP   8192
#define NS   2048
#define NK   16
#define DIN  64
#define DOUT 128
#define BN_EPS 1e-5f

// ---------------- K0: fold BN into weights, transpose to [k][o] ----------------
__global__ void fold_weights_kernel(const float* __restrict__ W, const float* __restrict__ bias,
                                    const float* __restrict__ gamma, const float* __restrict__ beta,
                                    const float* __restrict__ rmean, const float* __restrict__ rvar,
                                    float* __restrict__ Wt, float* __restrict__ Cb)
{
    int i = blockIdx.x * 256 + threadIdx.x;
    if (i < DIN * DOUT) {
        int o = i & (DOUT - 1);
        int k = i >> 7;
        float sc = gamma[o] * rsqrtf(rvar[o] + BN_EPS);
        Wt[i] = W[o * DIN + k] * sc;            // Wt[k*128 + o]
        if (i < DOUT) {
            Cb[i] = (bias[i] - rmean[i]) * sc + beta[i];
        }
    }
}

// ---------------- K1: farthest point sampling (1 block per batch) ----------------
// 512 threads x 16 pts/thread: arrays register-resident (~110 VGPR < 256 cap
// for 2 waves/SIMD), 8-partial reduce, NO global store inside the loop (the
// vmcnt(0) drain before s_barrier was gating every step). Selected indices go
// to LDS; coords written once at the end.
#define FT 512
#define FP (NP / FT)   // 16 points per thread
#define FW (FT / 64)   // 8 waves

__global__ __launch_bounds__(FT, 1)
void fps_kernel(const float* __restrict__ coords, float* __restrict__ out_coords)
{
#pragma clang fp contract(off)
    __shared__ float sx[NP], sy[NP], sz[NP];   // 96 KB
    __shared__ int   sel[NS];                  // 8 KB
    __shared__ float rv[2][FW];
    __shared__ int   ri[2][FW];

    const int b = blockIdx.x, t = threadIdx.x;
    const float* cb = coords + (size_t)b * NP * 3;

    for (int i = t; i < NP; i += FT) {
        sx[i] = cb[i * 3 + 0];
        sy[i] = cb[i * 3 + 1];
        sz[i] = cb[i * 3 + 2];
    }
    __syncthreads();

    float px[FP], py[FP], pz[FP], dist[FP];
#pragma unroll
    for (int k = 0; k < FP; ++k) {
        int i = t + k * FT;
        px[k] = sx[i]; py[k] = sy[i]; pz[k] = sz[i];
        dist[k] = 1e10f;
    }

    const int wave = t >> 6, lane = t & 63;
    int cur = 0;

    for (int s = 0; s < NS; ++s) {
        if (t == 0) sel[s] = cur;              // LDS write: cheap lgkm drain, no vmcnt
        float cx = sx[cur], cy = sy[cur], cz = sz[cur];
        // update min-dist + local argmax (strict >, ascending k -> smallest idx wins)
        float m = -1.0f; int kk = 0;
#pragma unroll
        for (int k = 0; k < FP; ++k) {
            float dx = px[k] - cx, dy = py[k] - cy, dz = pz[k] - cz;
            float d = ((dx * dx) + (dy * dy)) + (dz * dz);
            float nd = dist[k] < d ? dist[k] : d;
            dist[k] = nd;
            if (nd > m) { m = nd; kk = k; }
        }
        int li = t + kk * FT;
        // wave reduce: max value, tie -> min index
#pragma unroll
        for (int off = 32; off >= 1; off >>= 1) {
            float om = __shfl_xor(m, off);
            int   oi = __shfl_xor(li, off);
            if (om > m || (om == m && oi < li)) { m = om; li = oi; }
        }
        int pb = s & 1;
        if (lane == 0) { rv[pb][wave] = m; ri[pb][wave] = li; }
        __syncthreads();
        // every thread redundantly scans 8 wave-partials (LDS broadcast reads)
        float bm = rv[pb][0]; int bi = ri[pb][0];
#pragma unroll
        for (int w = 1; w < FW; ++w) {
            float vm = rv[pb][w]; int vi = ri[pb][w];
            if (vm > bm || (vm == bm && vi < bi)) { bm = vm; bi = vi; }
        }
        cur = bi;
    }
    __syncthreads();

    // single coalesced write of all selected coords
    float* ocb = out_coords + (size_t)b * NS * 3;
    for (int i = t; i < NS; i += FT) {
        int idx = sel[i];
        ocb[i * 3 + 0] = sx[idx];
        ocb[i * 3 + 1] = sy[idx];
        ocb[i * 3 + 2] = sz[idx];
    }
}

// ---------------- K2: pointwise MLP (conv1x1 + folded BN + relu) ----------------
__global__ __launch_bounds__(256)
void mlp_kernel(const float* __restrict__ feat, const float* __restrict__ Wt,
                const float* __restrict__ Cb, float* __restrict__ h)
{
    __shared__ float sf[2][DIN];
    const int t = threadIdx.x;
    const int o = t & (DOUT - 1);
    const int r2 = t >> 7;
    const size_t row0 = (size_t)blockIdx.x * 2;

    if (t < 2 * DIN) sf[t >> 6][t & 63] = feat[row0 * DIN + t];
    __syncthreads();

    float acc = Cb[o];
    const float4* f4 = (const float4*)sf[r2];
#pragma unroll
    for (int k4 = 0; k4 < DIN / 4; ++k4) {
        float4 f = f4[k4];
        acc = fmaf(f.x, Wt[(k4 * 4 + 0) * DOUT + o], acc);
        acc = fmaf(f.y, Wt[(k4 * 4 + 1) * DOUT + o], acc);
        acc = fmaf(f.z, Wt[(k4 * 4 + 2) * DOUT + o], acc);
        acc = fmaf(f.w, Wt[(k4 * 4 + 3) * DOUT + o], acc);
    }
    h[(row0 + r2) * DOUT + o] = fmaxf(acc, 0.0f);
}

// ---------------- K3: exact KNN (block per query, radix-cut + parallel rank-select) ----------------
#define KT 256
#define KJ (NP / KT)   // 32
#define NBINS 256
#define MAXC 512

__global__ __launch_bounds__(KT)
void knn_kernel(const float* __restrict__ coords, const float* __restrict__ qc,
                int* __restrict__ knn)
{
#pragma clang fp contract(off)
    __shared__ float sdist[NP];
    __shared__ unsigned hist[NBINS];
    __shared__ float cd[MAXC];
    __shared__ int   ci[MAXC];
    __shared__ unsigned ccnt;
    __shared__ int s_cut;

    const int q = blockIdx.x;
    const int b = q >> 11;
    const int t = threadIdx.x;
    const float* cb = coords + (size_t)b * NP * 3;
    const float qx = qc[(size_t)q * 3 + 0];
    const float qy = qc[(size_t)q * 3 + 1];
    const float qz = qc[(size_t)q * 3 + 2];

    for (int i = t; i < NBINS; i += KT) hist[i] = 0;
    if (t == 0) ccnt = 0;
    __syncthreads();

    for (int j = 0; j < KJ; ++j) {
        int i = t + j * KT;
        float dx = cb[i * 3 + 0] - qx, dy = cb[i * 3 + 1] - qy, dz = cb[i * 3 + 2] - qz;
        float d = ((dx * dx) + (dy * dy)) + (dz * dz);
        sdist[i] = d;
        atomicAdd(&hist[__float_as_uint(d) >> 23], 1u);   // positive floats: exponent bins
    }
    __syncthreads();

    // one wave finds the cut bin (cum count crosses NK)
    if (t < 64) {
        unsigned c0 = hist[t * 4 + 0], c1 = hist[t * 4 + 1];
        unsigned c2 = hist[t * 4 + 2], c3 = hist[t * 4 + 3];
        unsigned lsum = c0 + c1 + c2 + c3;
        unsigned incl = lsum;
#pragma unroll
        for (int off = 1; off < 64; off <<= 1) {
            unsigned n = __shfl_up(incl, off);
            if (t >= off) incl += n;
        }
        unsigned run = incl - lsum;
        if (run < NK && run + c0 >= NK) s_cut = t * 4 + 0;
        run += c0;
        if (run < NK && run + c1 >= NK) s_cut = t * 4 + 1;
        run += c1;
        if (run < NK && run + c2 >= NK) s_cut = t * 4 + 2;
        run += c2;
        if (run < NK && run + c3 >= NK) s_cut = t * 4 + 3;
    }
    __syncthreads();

    const int cut = s_cut;
    for (int j = 0; j < KJ; ++j) {
        int i = t + j * KT;
        float d = sdist[i];
        if ((int)(__float_as_uint(d) >> 23) <= cut) {
            unsigned p = atomicAdd(&ccnt, 1u);
            if (p < MAXC) { cd[p] = d; ci[p] = i; }
        }
    }
    __syncthreads();

    // parallel rank-select: candidate's rank = #{(dj,ij) < (d,i)} lexicographic.
    // Ranks are unique; rank < NK writes its slot directly. One pass, no serial tail.
    int cnt = (int)(ccnt < (unsigned)MAXC ? ccnt : (unsigned)MAXC);
    for (int p = t; p < cnt; p += KT) {
        float d = cd[p]; int idx = ci[p];
        int rank = 0;
        for (int j = 0; j < cnt; ++j) {
            float dj = cd[j]; int ij = ci[j];
            rank += (dj < d || (dj == d && ij < idx)) ? 1 : 0;
        }
        if (rank < NK) knn[(size_t)q * NK + rank] = idx;
    }
}

// ---------------- K4: gather precomputed h + max-pool ----------------
__global__ __launch_bounds__(128)
void gather_max_kernel(const float* __restrict__ h, const int* __restrict__ knn,
                       float* __restrict__ outF)
{
    const int q = blockIdx.x, o = threadIdx.x, b = q >> 11;
    __shared__ int sidx[NK];
    if (o < NK) sidx[o] = knn[(size_t)q * NK + o];
    __syncthreads();
    float m = -3.4e38f;
#pragma unroll
    for (int n = 0; n < NK; ++n) {
        float v = h[((size_t)b * NP + sidx[n]) * DOUT + o];
        m = fmaxf(m, v);
    }
    outF[(size_t)q * DOUT + o] = m;
}

// ---------------- K4': fallback if ws too small — fused gather + MLP + max ----------------
__global__ __launch_bounds__(128)
void fused_gather_mlp_kernel(const float* __restrict__ feat, const float* __restrict__ Wt,
                             const float* __restrict__ Cb, const int* __restrict__ knn,
                             float* __restrict__ outF)
{
    const int q = blockIdx.x, o = threadIdx.x, b = q >> 11;
    __shared__ int sidx[NK];
    __shared__ float sf[NK][DIN];
    if (o < NK) sidx[o] = knn[(size_t)q * NK + o];
    __syncthreads();
    for (int j = o; j < NK * DIN; j += 128) {
        int n = j >> 6;
        sf[n][j & 63] = feat[((size_t)b * NP + sidx[n]) * DIN + (j & 63)];
    }
    __syncthreads();
    const float cb0 = Cb[o];
    float m = -3.4e38f;
    for (int n = 0; n < NK; ++n) {
        float acc = cb0;
        const float4* f4 = (const float4*)sf[n];
#pragma unroll
        for (int k4 = 0; k4 < DIN / 4; ++k4) {
            float4 f = f4[k4];
            acc = fmaf(f.x, Wt[(k4 * 4 + 0) * DOUT + o], acc);
            acc = fmaf(f.y, Wt[(k4 * 4 + 1) * DOUT + o], acc);
            acc = fmaf(f.z, Wt[(k4 * 4 + 2) * DOUT + o], acc);
            acc = fmaf(f.w, Wt[(k4 * 4 + 3) * DOUT + o], acc);
        }
        m = fmaxf(m, fmaxf(acc, 0.0f));
    }
    outF[(size_t)q * DOUT + o] = m;
}

extern "C" void kernel_launch(void* const* d_in, const int* in_sizes, int n_in,
                              void* d_out, int out_size, void* d_ws, size_t ws_size,
                              hipStream_t stream)
{
    const float* coords = (const float*)d_in[0];
    const float* feat   = (const float*)d_in[1];
    const float* W      = (const float*)d_in[2];
    const float* bias   = (const float*)d_in[3];
    const float* gamma  = (const float*)d_in[4];
    const float* beta   = (const float*)d_in[5];
    const float* rmean  = (const float*)d_in[6];
    const float* rvar   = (const float*)d_in[7];

    float* out_coords = (float*)d_out;                    // [8,2048,3]
    float* out_feat   = out_coords + (size_t)NB * NS * 3; // [8,2048,128]

    char* ws = (char*)d_ws;
    float* Wt = (float*)ws;                                   // 32 KB
    float* Cb = (float*)(ws + 32768);                         // 512 B
    int*   knn = (int*)(ws + 65536);                          // 1 MB
    size_t knn_bytes = (size_t)NB * NS * NK * 4;
    float* h = (float*)(ws + 65536 + knn_bytes);              // 33.5 MB
    size_t need_h = (size_t)NB * NP * DOUT * 4;
    bool pathA = ws_size >= 65536 + knn_bytes + need_h;

    fold_weights_kernel<<<(DIN * DOUT + 255) / 256, 256, 0, stream>>>(
        W, bias, gamma, beta, rmean, rvar, Wt, Cb);
    if (pathA)
        mlp_kernel<<<NB * NP / 2, 256, 0, stream>>>(feat, Wt, Cb, h);
    fps_kernel<<<NB, FT, 0, stream>>>(coords, out_coords);
    knn_kernel<<<NB * NS, KT, 0, stream>>>(coords, out_coords, knn);
    if (pathA)
        gather_max_kernel<<<NB * NS, 128, 0, stream>>>(h, knn, out_feat);
    else
        fused_gather_mlp_kernel<<<NB * NS, 128, 0, stream>>>(feat, Wt, Cb, knn, out_feat);
}

// Round 4
// 2496.228 us; speedup vs baseline: 2.0171x; 1.5273x over previous
//
#include <hip/hip_runtime.h>

#define NB   8
#define NP   8192
#define NS   2048
#define NK   16
#define DIN  64
#define DOUT 128
#define BN_EPS 1e-5f

// ---------------- K0: fold BN into weights, transpose to [k][o] ----------------
__global__ void fold_weights_kernel(const float* __restrict__ W, const float* __restrict__ bias,
                                    const float* __restrict__ gamma, const float* __restrict__ beta,
                                    const float* __restrict__ rmean, const float* __restrict__ rvar,
                                    float* __restrict__ Wt, float* __restrict__ Cb)
{
    int i = blockIdx.x * 256 + threadIdx.x;
    if (i < DIN * DOUT) {
        int o = i & (DOUT - 1);
        int k = i >> 7;
        float sc = gamma[o] * rsqrtf(rvar[o] + BN_EPS);
        Wt[i] = W[o * DIN + k] * sc;            // Wt[k*128 + o]
        if (i < DOUT) {
            Cb[i] = (bias[i] - rmean[i]) * sc + beta[i];
        }
    }
}

// ---------------- DPP-based wave argmax combine (VALU pipe, not LDS pipe) ------
// packed key: hi = float bits of dist (dist >= 0 -> monotone), lo = ~index
// max(packed) == (max dist, tie -> min index). Associative+commutative.
template<int CTRL, int RMASK>
__device__ __forceinline__ void dpp_comb(unsigned &hi, unsigned &lo)
{
    unsigned th = (unsigned)__builtin_amdgcn_update_dpp((int)hi, (int)hi, CTRL, RMASK, 0xF, false);
    unsigned tl = (unsigned)__builtin_amdgcn_update_dpp((int)lo, (int)lo, CTRL, RMASK, 0xF, false);
    bool gt = (th > hi) || (th == hi && tl > lo);
    hi = gt ? th : hi;
    lo = gt ? tl : lo;
}

// ---------------- K1: farthest point sampling (1 block per batch) ----------------
// 512 threads x 16 pts/thread (register-resident, VGPR~90). Wave argmax via DPP
// (quad_perm xor1/xor2, row_ror:4/8 -> every lane has row max; bcast15/31 ->
// lane 63 has wave max). Cross-wave: 8 packed u64 partials in LDS, all threads
// redundantly scan. One barrier per step, double-buffered partials.
#define FT 512
#define FP (NP / FT)   // 16 points per thread
#define FW (FT / 64)   // 8 waves

__global__ __launch_bounds__(FT, 1)
void fps_kernel(const float* __restrict__ coords, float* __restrict__ out_coords)
{
#pragma clang fp contract(off)
    __shared__ float sx[NP], sy[NP], sz[NP];   // 96 KB
    __shared__ int   sel[NS];                  // 8 KB
    __shared__ unsigned long long rv64[2][FW];

    const int b = blockIdx.x, t = threadIdx.x;
    const float* cb = coords + (size_t)b * NP * 3;

    for (int i = t; i < NP; i += FT) {
        sx[i] = cb[i * 3 + 0];
        sy[i] = cb[i * 3 + 1];
        sz[i] = cb[i * 3 + 2];
    }
    __syncthreads();

    float px[FP], py[FP], pz[FP], dist[FP];
#pragma unroll
    for (int k = 0; k < FP; ++k) {
        int i = t + k * FT;
        px[k] = sx[i]; py[k] = sy[i]; pz[k] = sz[i];
        dist[k] = 1e10f;
    }

    const int wave = t >> 6, lane = t & 63;
    int cur = 0;

    for (int s = 0; s < NS; ++s) {
        if (t == 0) sel[s] = cur;
        float cx = sx[cur], cy = sy[cur], cz = sz[cur];
        // update min-dist + local argmax (strict >, ascending k -> smallest idx wins)
        float m = -1.0f; int kk = 0;
#pragma unroll
        for (int k = 0; k < FP; ++k) {
            float dx = px[k] - cx, dy = py[k] - cy, dz = pz[k] - cz;
            float d = ((dx * dx) + (dy * dy)) + (dz * dz);
            float nd = dist[k] < d ? dist[k] : d;
            dist[k] = nd;
            if (nd > m) { m = nd; kk = k; }
        }
        // pack: m >= 0 always (all nd >= 0), so float bits are order-preserving
        unsigned hi = __float_as_uint(m);
        unsigned lo = ~(unsigned)(t + kk * FT);
        // wave argmax via DPP (VALU-latency cross-lane)
        dpp_comb<0xB1,  0xF>(hi, lo);   // quad_perm [1,0,3,2] : xor 1
        dpp_comb<0x4E,  0xF>(hi, lo);   // quad_perm [2,3,0,1] : xor 2
        dpp_comb<0x124, 0xF>(hi, lo);   // row_ror:4
        dpp_comb<0x128, 0xF>(hi, lo);   // row_ror:8  -> all lanes have row(16) max
        dpp_comb<0x142, 0xA>(hi, lo);   // row_bcast15 -> rows 1,3 get pair max
        dpp_comb<0x143, 0xC>(hi, lo);   // row_bcast31 -> row 3 gets wave max
        int pb = s & 1;
        if (lane == 63) rv64[pb][wave] = ((unsigned long long)hi << 32) | lo;
        __syncthreads();
        // all threads redundantly scan 8 packed partials
        unsigned long long best = rv64[pb][0];
#pragma unroll
        for (int w = 1; w < FW; ++w) {
            unsigned long long v = rv64[pb][w];
            if (v > best) best = v;
        }
        cur = (int)(~(unsigned)best);
    }
    __syncthreads();

    // single coalesced write of all selected coords
    float* ocb = out_coords + (size_t)b * NS * 3;
    for (int i = t; i < NS; i += FT) {
        int idx = sel[i];
        ocb[i * 3 + 0] = sx[idx];
        ocb[i * 3 + 1] = sy[idx];
        ocb[i * 3 + 2] = sz[idx];
    }
}

// ---------------- K2: pointwise MLP (conv1x1 + folded BN + relu) ----------------
__global__ __launch_bounds__(256)
void mlp_kernel(const float* __restrict__ feat, const float* __restrict__ Wt,
                const float* __restrict__ Cb, float* __restrict__ h)
{
    __shared__ float sf[2][DIN];
    const int t = threadIdx.x;
    const int o = t & (DOUT - 1);
    const int r2 = t >> 7;
    const size_t row0 = (size_t)blockIdx.x * 2;

    if (t < 2 * DIN) sf[t >> 6][t & 63] = feat[row0 * DIN + t];
    __syncthreads();

    float acc = Cb[o];
    const float4* f4 = (const float4*)sf[r2];
#pragma unroll
    for (int k4 = 0; k4 < DIN / 4; ++k4) {
        float4 f = f4[k4];
        acc = fmaf(f.x, Wt[(k4 * 4 + 0) * DOUT + o], acc);
        acc = fmaf(f.y, Wt[(k4 * 4 + 1) * DOUT + o], acc);
        acc = fmaf(f.z, Wt[(k4 * 4 + 2) * DOUT + o], acc);
        acc = fmaf(f.w, Wt[(k4 * 4 + 3) * DOUT + o], acc);
    }
    h[(row0 + r2) * DOUT + o] = fmaxf(acc, 0.0f);
}

// ---------------- K3: exact KNN (radix-cut + parallel rank-select) ----------------
// Histogram: 64 clamped exponent bins x 32 lane-copies, layout hist[copy][bin]
// so bank = bin%32 and same-address atomic collisions are <=2-way (was up to
// 64-way on hot bins -> 5e7 SQ_LDS_BANK_CONFLICT).
#define KT 256
#define KJ (NP / KT)   // 32
#define KBINS 64
#define MAXC 512

__device__ __forceinline__ int knn_bin(float d)
{
    int e = (int)(__float_as_uint(d) >> 23) - 90;   // monotone, clamp far outside data range
    return e < 0 ? 0 : (e > 63 ? 63 : e);
}

__global__ __launch_bounds__(KT)
void knn_kernel(const float* __restrict__ coords, const float* __restrict__ qc,
                int* __restrict__ knn)
{
#pragma clang fp contract(off)
    __shared__ float sdist[NP];                 // 32 KB
    __shared__ unsigned hist[32][KBINS];        // 8 KB
    __shared__ float cd[MAXC];
    __shared__ int   ci[MAXC];
    __shared__ unsigned ccnt;
    __shared__ int s_cut;

    const int q = blockIdx.x;
    const int b = q >> 11;
    const int t = threadIdx.x;
    const int c = t & 31;
    const float* cb = coords + (size_t)b * NP * 3;
    const float qx = qc[(size_t)q * 3 + 0];
    const float qy = qc[(size_t)q * 3 + 1];
    const float qz = qc[(size_t)q * 3 + 2];

    for (int i = t; i < 32 * KBINS; i += KT) ((unsigned*)hist)[i] = 0;
    if (t == 0) ccnt = 0;
    __syncthreads();

    for (int j = 0; j < KJ; ++j) {
        int i = t + j * KT;
        float dx = cb[i * 3 + 0] - qx, dy = cb[i * 3 + 1] - qy, dz = cb[i * 3 + 2] - qz;
        float d = ((dx * dx) + (dy * dy)) + (dz * dz);
        sdist[i] = d;
        atomicAdd(&hist[c][knn_bin(d)], 1u);
    }
    __syncthreads();

    // one wave: fold 32 copies per bin + prefix scan -> cut bin (cum crosses NK)
    if (t < 64) {
        unsigned total = 0;
#pragma unroll
        for (int cc = 0; cc < 32; ++cc) total += hist[cc][t];
        unsigned incl = total;
#pragma unroll
        for (int off = 1; off < 64; off <<= 1) {
            unsigned n = __shfl_up(incl, off);
            if (t >= off) incl += n;
        }
        unsigned excl = incl - total;
        if (excl < NK && incl >= NK) s_cut = t;
    }
    __syncthreads();

    const int cut = s_cut;
    for (int j = 0; j < KJ; ++j) {
        int i = t + j * KT;
        float d = sdist[i];
        if (knn_bin(d) <= cut) {
            unsigned p = atomicAdd(&ccnt, 1u);
            if (p < MAXC) { cd[p] = d; ci[p] = i; }
        }
    }
    __syncthreads();

    // parallel rank-select: rank = #{(dj,ij) < (d,i)} lexicographic; unique ranks
    int cnt = (int)(ccnt < (unsigned)MAXC ? ccnt : (unsigned)MAXC);
    for (int p = t; p < cnt; p += KT) {
        float d = cd[p]; int idx = ci[p];
        int rank = 0;
        for (int j = 0; j < cnt; ++j) {
            float dj = cd[j]; int ij = ci[j];
            rank += (dj < d || (dj == d && ij < idx)) ? 1 : 0;
        }
        if (rank < NK) knn[(size_t)q * NK + rank] = idx;
    }
}

// ---------------- K4: gather precomputed h + max-pool ----------------
__global__ __launch_bounds__(128)
void gather_max_kernel(const float* __restrict__ h, const int* __restrict__ knn,
                       float* __restrict__ outF)
{
    const int q = blockIdx.x, o = threadIdx.x, b = q >> 11;
    __shared__ int sidx[NK];
    if (o < NK) sidx[o] = knn[(size_t)q * NK + o];
    __syncthreads();
    float m = -3.4e38f;
#pragma unroll
    for (int n = 0; n < NK; ++n) {
        float v = h[((size_t)b * NP + sidx[n]) * DOUT + o];
        m = fmaxf(m, v);
    }
    outF[(size_t)q * DOUT + o] = m;
}

// ---------------- K4': fallback if ws too small — fused gather + MLP + max ----------------
__global__ __launch_bounds__(128)
void fused_gather_mlp_kernel(const float* __restrict__ feat, const float* __restrict__ Wt,
                             const float* __restrict__ Cb, const int* __restrict__ knn,
                             float* __restrict__ outF)
{
    const int q = blockIdx.x, o = threadIdx.x, b = q >> 11;
    __shared__ int sidx[NK];
    __shared__ float sf[NK][DIN];
    if (o < NK) sidx[o] = knn[(size_t)q * NK + o];
    __syncthreads();
    for (int j = o; j < NK * DIN; j += 128) {
        int n = j >> 6;
        sf[n][j & 63] = feat[((size_t)b * NP + sidx[n]) * DIN + (j & 63)];
    }
    __syncthreads();
    const float cb0 = Cb[o];
    float m = -3.4e38f;
    for (int n = 0; n < NK; ++n) {
        float acc = cb0;
        const float4* f4 = (const float4*)sf[n];
#pragma unroll
        for (int k4 = 0; k4 < DIN / 4; ++k4) {
            float4 f = f4[k4];
            acc = fmaf(f.x, Wt[(k4 * 4 + 0) * DOUT + o], acc);
            acc = fmaf(f.y, Wt[(k4 * 4 + 1) * DOUT + o], acc);
            acc = fmaf(f.z, Wt[(k4 * 4 + 2) * DOUT + o], acc);
            acc = fmaf(f.w, Wt[(k4 * 4 + 3) * DOUT + o], acc);
        }
        m = fmaxf(m, fmaxf(acc, 0.0f));
    }
    outF[(size_t)q * DOUT + o] = m;
}

extern "C" void kernel_launch(void* const* d_in, const int* in_sizes, int n_in,
                              void* d_out, int out_size, void* d_ws, size_t ws_size,
                              hipStream_t stream)
{
    const float* coords = (const float*)d_in[0];
    const float* feat   = (const float*)d_in[1];
    const float* W      = (const float*)d_in[2];
    const float* bias   = (const float*)d_in[3];
    const float* gamma  = (const float*)d_in[4];
    const float* beta   = (const float*)d_in[5];
    const float* rmean  = (const float*)d_in[6];
    const float* rvar   = (const float*)d_in[7];

    float* out_coords = (float*)d_out;                    // [8,2048,3]
    float* out_feat   = out_coords + (size_t)NB * NS * 3; // [8,2048,128]

    char* ws = (char*)d_ws;
    float* Wt = (float*)ws;                                   // 32 KB
    float* Cb = (float*)(ws + 32768);                         // 512 B
    int*   knn = (int*)(ws + 65536);                          // 1 MB
    size_t knn_bytes = (size_t)NB * NS * NK * 4;
    float* h = (float*)(ws + 65536 + knn_bytes);              // 33.5 MB
    size_t need_h = (size_t)NB * NP * DOUT * 4;
    bool pathA = ws_size >= 65536 + knn_bytes + need_h;

    fold_weights_kernel<<<(DIN * DOUT + 255) / 256, 256, 0, stream>>>(
        W, bias, gamma, beta, rmean, rvar, Wt, Cb);
    if (pathA)
        mlp_kernel<<<NB * NP / 2, 256, 0, stream>>>(feat, Wt, Cb, h);
    fps_kernel<<<NB, FT, 0, stream>>>(coords, out_coords);
    knn_kernel<<<NB * NS, KT, 0, stream>>>(coords, out_coords, knn);
    if (pathA)
        gather_max_kernel<<<NB * NS, 128, 0, stream>>>(h, knn, out_feat);
    else
        fused_gather_mlp_kernel<<<NB * NS, 128, 0, stream>>>(feat, Wt, Cb, knn, out_feat);
}

// Round 5
// 2103.025 us; speedup vs baseline: 2.3942x; 1.1870x over previous
//
#include <hip/hip_runtime.h>

#define NB   8
#define NP   8192
#define NS   2048
#define NK   16
#define DIN  64
#define DOUT 128
#define BN_EPS 1e-5f

// ---------------- K0: fold BN into weights, transpose to [k][o] ----------------
__global__ void fold_weights_kernel(const float* __restrict__ W, const float* __restrict__ bias,
                                    const float* __restrict__ gamma, const float* __restrict__ beta,
                                    const float* __restrict__ rmean, const float* __restrict__ rvar,
                                    float* __restrict__ Wt, float* __restrict__ Cb)
{
    int i = blockIdx.x * 256 + threadIdx.x;
    if (i < DIN * DOUT) {
        int o = i & (DOUT - 1);
        int k = i >> 7;
        float sc = gamma[o] * rsqrtf(rvar[o] + BN_EPS);
        Wt[i] = W[o * DIN + k] * sc;            // Wt[k*128 + o]
        if (i < DOUT) {
            Cb[i] = (bias[i] - rmean[i]) * sc + beta[i];
        }
    }
}

// ---------------- f64-packed argmax combine --------------------------------------
// packed u64 = (fp32 dist bits << 32) | ~idx, reinterpreted as double.
// Sign bit is 0 (dist >= 0 finite), so double ordering == u64 ordering:
// fmax == (max dist, tie -> min idx). One v_max_f64 per combine.
__device__ __forceinline__ double pack_di(float d, unsigned lo)
{
    unsigned long long u = ((unsigned long long)__float_as_uint(d) << 32) | lo;
    return __longlong_as_double((long long)u);
}

template<int CTRL, int RMASK>
__device__ __forceinline__ double dpp_max_f64(double v)
{
    unsigned long long u = (unsigned long long)__double_as_longlong(v);
    unsigned hi = (unsigned)(u >> 32), lo = (unsigned)u;
    unsigned th = (unsigned)__builtin_amdgcn_update_dpp((int)hi, (int)hi, CTRL, RMASK, 0xF, false);
    unsigned tl = (unsigned)__builtin_amdgcn_update_dpp((int)lo, (int)lo, CTRL, RMASK, 0xF, false);
    double o = __longlong_as_double((long long)(((unsigned long long)th << 32) | tl));
    return fmax(v, o);
}

// ---------------- K1: farthest point sampling (1 block per batch) ----------------
// 512 threads x 16 pts/thread, register-resident. Per-step serial chain:
// barrier -> ds_read_b64 partial[lane&7] -> 4 DPP f64-max levels (global winner
// on every lane) -> ds_read_b128 centroid -> dist loop (fmax f64 accumulate) ->
// 6 DPP f64-max levels -> lane63 ds_write partial. One barrier per step.
#define FT 512
#define FP (NP / FT)   // 16 points per thread
#define FW (FT / 64)   // 8 waves

__global__ __launch_bounds__(FT, 1)
void fps_kernel(const float* __restrict__ coords, float* __restrict__ out_coords)
{
#pragma clang fp contract(off)
    __shared__ float4 sxyz[NP];                // 128 KB, one ds_read_b128 per centroid
    __shared__ int    sel[NS];                 // 8 KB
    __shared__ unsigned long long rv64[2][FW];

    const int b = blockIdx.x, t = threadIdx.x;
    const float* cb = coords + (size_t)b * NP * 3;

    for (int i = t; i < NP; i += FT) {
        sxyz[i] = make_float4(cb[i * 3 + 0], cb[i * 3 + 1], cb[i * 3 + 2], 0.0f);
    }
    __syncthreads();

    float px[FP], py[FP], pz[FP], dist[FP];
#pragma unroll
    for (int k = 0; k < FP; ++k) {
        float4 p = sxyz[t + k * FT];
        px[k] = p.x; py[k] = p.y; pz[k] = p.z;
        dist[k] = 1e10f;
    }

    const int wave = t >> 6, lane = t & 63;
    const unsigned nt = ~(unsigned)t;          // ~(t + k*FT) == nt - k*FT
    int cur = 0;

    for (int s = 0; s < NS; ++s) {
        if (t == 0) sel[s] = cur;
        const float4 cc = sxyz[cur];
        const float cx = cc.x, cy = cc.y, cz = cc.z;

        // update min-dist + packed argmax (2 accumulators halve the dep chain)
        double best0 = 0.0, best1 = 0.0;
#pragma unroll
        for (int k = 0; k < FP; ++k) {
            float dx = px[k] - cx, dy = py[k] - cy, dz = pz[k] - cz;
            float d = ((dx * dx) + (dy * dy)) + (dz * dz);
            float nd = dist[k] < d ? dist[k] : d;
            dist[k] = nd;
            double pd = pack_di(nd, nt - (unsigned)(k * FT));
            if (k & 1) best1 = fmax(best1, pd);
            else       best0 = fmax(best0, pd);
        }
        double best = fmax(best0, best1);

        // wave argmax: 6 DPP f64-max levels -> lane 63 has wave max
        best = dpp_max_f64<0xB1,  0xF>(best);  // quad_perm xor1
        best = dpp_max_f64<0x4E,  0xF>(best);  // quad_perm xor2
        best = dpp_max_f64<0x124, 0xF>(best);  // row_ror:4
        best = dpp_max_f64<0x128, 0xF>(best);  // row_ror:8 -> row(16) max everywhere
        best = dpp_max_f64<0x142, 0xA>(best);  // row_bcast15
        best = dpp_max_f64<0x143, 0xC>(best);  // row_bcast31 -> lane63 = wave max

        int pb = s & 1;
        if (lane == 63) rv64[pb][wave] = (unsigned long long)__double_as_longlong(best);
        __syncthreads();

        // cross-wave: lane-indexed single b64 read (broadcast-friendly: 8 addrs,
        // 8 lanes each -> no conflicts), then 4 DPP levels over row of 16
        // (= 2 copies of the 8 partials) -> every lane holds the global winner.
        double g = __longlong_as_double((long long)rv64[pb][lane & 7]);
        g = dpp_max_f64<0xB1,  0xF>(g);
        g = dpp_max_f64<0x4E,  0xF>(g);
        g = dpp_max_f64<0x124, 0xF>(g);
        g = dpp_max_f64<0x128, 0xF>(g);
        cur = (int)~(unsigned)(unsigned long long)__double_as_longlong(g);
    }
    __syncthreads();

    // single coalesced write of all selected coords
    float* ocb = out_coords + (size_t)b * NS * 3;
    for (int i = t; i < NS; i += FT) {
        float4 p = sxyz[sel[i]];
        ocb[i * 3 + 0] = p.x;
        ocb[i * 3 + 1] = p.y;
        ocb[i * 3 + 2] = p.z;
    }
}

// ---------------- K2: pointwise MLP (conv1x1 + folded BN + relu) ----------------
__global__ __launch_bounds__(256)
void mlp_kernel(const float* __restrict__ feat, const float* __restrict__ Wt,
                const float* __restrict__ Cb, float* __restrict__ h)
{
    __shared__ float sf[2][DIN];
    const int t = threadIdx.x;
    const int o = t & (DOUT - 1);
    const int r2 = t >> 7;
    const size_t row0 = (size_t)blockIdx.x * 2;

    if (t < 2 * DIN) sf[t >> 6][t & 63] = feat[row0 * DIN + t];
    __syncthreads();

    float acc = Cb[o];
    const float4* f4 = (const float4*)sf[r2];
#pragma unroll
    for (int k4 = 0; k4 < DIN / 4; ++k4) {
        float4 f = f4[k4];
        acc = fmaf(f.x, Wt[(k4 * 4 + 0) * DOUT + o], acc);
        acc = fmaf(f.y, Wt[(k4 * 4 + 1) * DOUT + o], acc);
        acc = fmaf(f.z, Wt[(k4 * 4 + 2) * DOUT + o], acc);
        acc = fmaf(f.w, Wt[(k4 * 4 + 3) * DOUT + o], acc);
    }
    h[(row0 + r2) * DOUT + o] = fmaxf(acc, 0.0f);
}

// ---------------- K3: exact KNN (radix-cut + parallel rank-select) ----------------
// Histogram: 64 clamped exponent bins x 32 lane-copies, layout hist[copy][bin]
// so bank = bin%32 and same-address atomic collisions are <=2-way.
#define KT 256
#define KJ (NP / KT)   // 32
#define KBINS 64
#define MAXC 512

__device__ __forceinline__ int knn_bin(float d)
{
    int e = (int)(__float_as_uint(d) >> 23) - 90;   // monotone, clamp far outside data range
    return e < 0 ? 0 : (e > 63 ? 63 : e);
}

__global__ __launch_bounds__(KT)
void knn_kernel(const float* __restrict__ coords, const float* __restrict__ qc,
                int* __restrict__ knn)
{
#pragma clang fp contract(off)
    __shared__ float sdist[NP];                 // 32 KB
    __shared__ unsigned hist[32][KBINS];        // 8 KB
    __shared__ float cd[MAXC];
    __shared__ int   ci[MAXC];
    __shared__ unsigned ccnt;
    __shared__ int s_cut;

    const int q = blockIdx.x;
    const int b = q >> 11;
    const int t = threadIdx.x;
    const int c = t & 31;
    const float* cb = coords + (size_t)b * NP * 3;
    const float qx = qc[(size_t)q * 3 + 0];
    const float qy = qc[(size_t)q * 3 + 1];
    const float qz = qc[(size_t)q * 3 + 2];

    for (int i = t; i < 32 * KBINS; i += KT) ((unsigned*)hist)[i] = 0;
    if (t == 0) ccnt = 0;
    __syncthreads();

    for (int j = 0; j < KJ; ++j) {
        int i = t + j * KT;
        float dx = cb[i * 3 + 0] - qx, dy = cb[i * 3 + 1] - qy, dz = cb[i * 3 + 2] - qz;
        float d = ((dx * dx) + (dy * dy)) + (dz * dz);
        sdist[i] = d;
        atomicAdd(&hist[c][knn_bin(d)], 1u);
    }
    __syncthreads();

    // one wave: fold 32 copies per bin + prefix scan -> cut bin (cum crosses NK)
    if (t < 64) {
        unsigned total = 0;
#pragma unroll
        for (int cc = 0; cc < 32; ++cc) total += hist[cc][t];
        unsigned incl = total;
#pragma unroll
        for (int off = 1; off < 64; off <<= 1) {
            unsigned n = __shfl_up(incl, off);
            if (t >= off) incl += n;
        }
        unsigned excl = incl - total;
        if (excl < NK && incl >= NK) s_cut = t;
    }
    __syncthreads();

    const int cut = s_cut;
    for (int j = 0; j < KJ; ++j) {
        int i = t + j * KT;
        float d = sdist[i];
        if (knn_bin(d) <= cut) {
            unsigned p = atomicAdd(&ccnt, 1u);
            if (p < MAXC) { cd[p] = d; ci[p] = i; }
        }
    }
    __syncthreads();

    // parallel rank-select: rank = #{(dj,ij) < (d,i)} lexicographic; unique ranks
    int cnt = (int)(ccnt < (unsigned)MAXC ? ccnt : (unsigned)MAXC);
    for (int p = t; p < cnt; p += KT) {
        float d = cd[p]; int idx = ci[p];
        int rank = 0;
        for (int j = 0; j < cnt; ++j) {
            float dj = cd[j]; int ij = ci[j];
            rank += (dj < d || (dj == d && ij < idx)) ? 1 : 0;
        }
        if (rank < NK) knn[(size_t)q * NK + rank] = idx;
    }
}

// ---------------- K4: gather precomputed h + max-pool ----------------
__global__ __launch_bounds__(128)
void gather_max_kernel(const float* __restrict__ h, const int* __restrict__ knn,
                       float* __restrict__ outF)
{
    const int q = blockIdx.x, o = threadIdx.x, b = q >> 11;
    __shared__ int sidx[NK];
    if (o < NK) sidx[o] = knn[(size_t)q * NK + o];
    __syncthreads();
    float m = -3.4e38f;
#pragma unroll
    for (int n = 0; n < NK; ++n) {
        float v = h[((size_t)b * NP + sidx[n]) * DOUT + o];
        m = fmaxf(m, v);
    }
    outF[(size_t)q * DOUT + o] = m;
}

// ---------------- K4': fallback if ws too small — fused gather + MLP + max ----------------
__global__ __launch_bounds__(128)
void fused_gather_mlp_kernel(const float* __restrict__ feat, const float* __restrict__ Wt,
                             const float* __restrict__ Cb, const int* __restrict__ knn,
                             float* __restrict__ outF)
{
    const int q = blockIdx.x, o = threadIdx.x, b = q >> 11;
    __shared__ int sidx[NK];
    __shared__ float sf[NK][DIN];
    if (o < NK) sidx[o] = knn[(size_t)q * NK + o];
    __syncthreads();
    for (int j = o; j < NK * DIN; j += 128) {
        int n = j >> 6;
        sf[n][j & 63] = feat[((size_t)b * NP + sidx[n]) * DIN + (j & 63)];
    }
    __syncthreads();
    const float cb0 = Cb[o];
    float m = -3.4e38f;
    for (int n = 0; n < NK; ++n) {
        float acc = cb0;
        const float4* f4 = (const float4*)sf[n];
#pragma unroll
        for (int k4 = 0; k4 < DIN / 4; ++k4) {
            float4 f = f4[k4];
            acc = fmaf(f.x, Wt[(k4 * 4 + 0) * DOUT + o], acc);
            acc = fmaf(f.y, Wt[(k4 * 4 + 1) * DOUT + o], acc);
            acc = fmaf(f.z, Wt[(k4 * 4 + 2) * DOUT + o], acc);
            acc = fmaf(f.w, Wt[(k4 * 4 + 3) * DOUT + o], acc);
        }
        m = fmaxf(m, fmaxf(acc, 0.0f));
    }
    outF[(size_t)q * DOUT + o] = m;
}

extern "C" void kernel_launch(void* const* d_in, const int* in_sizes, int n_in,
                              void* d_out, int out_size, void* d_ws, size_t ws_size,
                              hipStream_t stream)
{
    const float* coords = (const float*)d_in[0];
    const float* feat   = (const float*)d_in[1];
    const float* W      = (const float*)d_in[2];
    const float* bias   = (const float*)d_in[3];
    const float* gamma  = (const float*)d_in[4];
    const float* beta   = (const float*)d_in[5];
    const float* rmean  = (const float*)d_in[6];
    const float* rvar   = (const float*)d_in[7];

    float* out_coords = (float*)d_out;                    // [8,2048,3]
    float* out_feat   = out_coords + (size_t)NB * NS * 3; // [8,2048,128]

    char* ws = (char*)d_ws;
    float* Wt = (float*)ws;                                   // 32 KB
    float* Cb = (float*)(ws + 32768);                         // 512 B
    int*   knn = (int*)(ws + 65536);                          // 1 MB
    size_t knn_bytes = (size_t)NB * NS * NK * 4;
    float* h = (float*)(ws + 65536 + knn_bytes);              // 33.5 MB
    size_t need_h = (size_t)NB * NP * DOUT * 4;
    bool pathA = ws_size >= 65536 + knn_bytes + need_h;

    fold_weights_kernel<<<(DIN * DOUT + 255) / 256, 256, 0, stream>>>(
        W, bias, gamma, beta, rmean, rvar, Wt, Cb);
    if (pathA)
        mlp_kernel<<<NB * NP / 2, 256, 0, stream>>>(feat, Wt, Cb, h);
    fps_kernel<<<NB, FT, 0, stream>>>(coords, out_coords);
    knn_kernel<<<NB * NS, KT, 0, stream>>>(coords, out_coords, knn);
    if (pathA)
        gather_max_kernel<<<NB * NS, 128, 0, stream>>>(h, knn, out_feat);
    else
        fused_gather_mlp_kernel<<<NB * NS, 128, 0, stream>>>(feat, Wt, Cb, knn, out_feat);
}